// Round 14
// baseline (3108.542 us; speedup 1.0000x reference)
//
#include <hip/hip_runtime.h>
#include <stdint.h>

#define NBATCH 128
#define NT     64
#define OBD    32
#define ACD    8
#define LDIM   128
#define HDIM   256

typedef _Float16 h2 __attribute__((ext_vector_type(2)));
typedef float    f4 __attribute__((ext_vector_type(4)));

#if defined(__has_builtin)
#  if __has_builtin(__builtin_amdgcn_fdot2)
#    define HAVE_FDOT2 1
#  endif
#endif

__device__ __forceinline__ float dot2f(h2 a, h2 b, float c) {
#ifdef HAVE_FDOT2
  return __builtin_amdgcn_fdot2(a, b, c, false);
#else
  return c + (float)a[0] * (float)b[0] + (float)a[1] * (float)b[1];
#endif
}

__device__ __forceinline__ h2 pkh(float a, float b) {
  h2 r; r[0] = (_Float16)a; r[1] = (_Float16)b; return r;
}

__device__ __forceinline__ h2 bch(float x) { return __builtin_bit_cast(h2, x); }
__device__ __forceinline__ float fch(h2 x) { return __builtin_bit_cast(float, x); }

__device__ __forceinline__ float sigmf(float x) { return 1.0f / (1.0f + expf(-x)); }

// ---- prep: Wd1 (f32 row-major) -> d_ws f16 chunk-major, 1024-thread
// geometry: main thread t owns rows {2(t>>3), +1}, K-slice (t&7)*32..+31.
// chunk j (0..7): row parity j&1, k-subrange (j>>1)*8.
__global__ void prep_w1(const float* __restrict__ Wd1, f4* __restrict__ ws4) {
  int idx = blockIdx.x * blockDim.x + threadIdx.x;   // 0..8191
  int j  = idx >> 10;
  int tt = idx & 1023;
  const float* src = Wd1 + (2 * (tt >> 3) + (j & 1)) * HDIM
                         + (tt & 7) * 32 + (j >> 1) * 8;
  f4 c;
  c.x = fch(pkh(src[0], src[1]));
  c.y = fch(pkh(src[2], src[3]));
  c.z = fch(pkh(src[4], src[5]));
  c.w = fch(pkh(src[6], src[7]));
  ws4[j * 1024 + tt] = c;
}

// 1024 threads / 16 waves = 4 waves/SIMD (r13 post-mortem: segments are
// latency/straggler-bound at 2 waves/SIMD -- pipes <45% busy, theory table
// eliminated spills/conflicts/LDS-throughput/vmcnt). Per-thread work halves,
// latency-hiding pool doubles. amdgpu_waves_per_eu(4,4) pins 1 block/CU so
// the allocator budget is 512/4 = 128 VGPRs (the ceiling it always enforces)
// -- resident state ~100 regs, NO spill (r4's 1024-thr attempt died on the
// 64-reg budget of 2-block residency).
//   stage1: pair G1=t>>3 (128), K1=t&7 (16 k) ; stage2: same G1/K1 (32 k)
//   stage3: pair G3=t>>4 (64),  K3=t&15 (16 k)
// LDS slices padded to distinct banks:
//   s_in16: 8 x ( 8 h2 + 4 pad), stride 12 dw -> bases mod32 {0,12,24,4,16,28,8,20}
//   s_a16 : 8 x (16 h2 + 4 pad), stride 20 dw -> {0,20,8,28,16,4,24,12}
//   s_b16 : 16 x ( 8 h2 + 4 pad), stride 12 dw -> 2-way alias (free, m136)
// GRU/decode/encoder keep the proven r13 mappings under t<NNN guards.
__global__ __attribute__((amdgpu_waves_per_eu(4, 4))) __launch_bounds__(1024)
void ode_rnn_kernel(const float* __restrict__ ob,   const float* __restrict__ acs,
                    const float* __restrict__ times,
                    const float* __restrict__ We0,  const float* __restrict__ be0,
                    const float* __restrict__ We1,  const float* __restrict__ be1,
                    const float* __restrict__ Wd0,  const float* __restrict__ bd0,
                    const float* __restrict__ bd1,
                    const float* __restrict__ Wd2,  const float* __restrict__ bd2,
                    const float* __restrict__ Wo0,  const float* __restrict__ bo0,
                    const float* __restrict__ Wo1,  const float* __restrict__ bo1,
                    const float* __restrict__ Wih,  const float* __restrict__ Whh,
                    const float* __restrict__ bih,  const float* __restrict__ bn,
                    const f4* __restrict__ ws4,
                    float* __restrict__ out)
{
  const int t  = threadIdx.x;
  const int b  = blockIdx.x;
  const int G1 = t >> 3, K1 = t & 7;    // stage1/2 row-pair + K-slice
  const int G3 = t >> 4, K3 = t & 15;   // stage3 row-pair + K-slice

  __shared__ __align__(16) float s_lat[LDIM];
  __shared__ __align__(16) float s_gr[LDIM];
  __shared__ __align__(16) float s_gz[LDIM];
  __shared__ __align__(16) float s_gin[LDIM];
  __shared__ __align__(16) float s_ghn[LDIM];
  __shared__ __align__(16) float s_tmp[HDIM];
  __shared__ __align__(16) float s_obs[OBD];
  __shared__ __align__(16) float s_times[NT];
  __shared__ __align__(16) float s_acs[NT * ACD];
  __shared__ __align__(16) h2    s_in16[96];    // 8 slices, stride 12 dw
  __shared__ __align__(16) h2    s_a16[160];    // 8 slices, stride 20 dw
  __shared__ __align__(16) h2    s_b16[192];    // 16 slices, stride 12 dw

  // ---- resident weights: Wd0/Wd2 row-pair x K-slice (16 h2 each) ----
  h2 w0[16], w2[16];
  {
    const float2* r0 = (const float2*)(Wd0 + (2 * G1) * LDIM + K1 * 16);
    const float2* r1 = (const float2*)(Wd0 + (2 * G1 + 1) * LDIM + K1 * 16);
#pragma unroll
    for (int i = 0; i < 8; ++i) {
      float2 u = r0[i], v = r1[i];
      w0[i] = pkh(u.x, u.y); w0[8 + i] = pkh(v.x, v.y);
    }
  }
  {
    const float2* r0 = (const float2*)(Wd2 + (2 * G3) * HDIM + K3 * 16);
    const float2* r1 = (const float2*)(Wd2 + (2 * G3 + 1) * HDIM + K3 * 16);
#pragma unroll
    for (int i = 0; i < 8; ++i) {
      float2 u = r0[i], v = r1[i];
      w2[i] = pkh(u.x, u.y); w2[8 + i] = pkh(v.x, v.y);
    }
  }
  const f4* wsb = ws4 + t;              // per-thread w1 stream base

  const float bb00 = bd0[2 * G1], bb01 = bd0[2 * G1 + 1];
  const float bb10 = bd1[2 * G1], bb11 = bd1[2 * G1 + 1];
  const float bb20 = bd2[2 * G3], bb21 = bd2[2 * G3 + 1];
  const float rb0  = (t < 512) ? bo0[t >> 1] : 0.0f;
  const float gA   = (t < 768) ? bih[t >> 1] : 0.0f;
  const float bnr  = (t < LDIM) ? bn[t] : 0.0f;

  float latr0 = 0.0f, latr1 = 0.0f;     // lat[2G3], lat[2G3+1]

  // ---- one Dopri5 substep; entry: s_in16 = packed lat, latr* = lat ----
  auto substep = [&](float hs) {
    float k00 = 0, k10 = 0, k20 = 0, k30 = 0, k40 = 0;
    float k01 = 0, k11 = 0, k21 = 0, k31 = 0, k41 = 0;
#pragma unroll
    for (int s = 0; s < 6; ++s) {
      // w1 prefetch chunks 0-3 (no deps; land by stage 2)
      f4 y0 = wsb[0 * 1024], y1 = wsb[1 * 1024];
      f4 y2 = wsb[2 * 1024], y3 = wsb[3 * 1024];
      float a0, a1, b0, b1, v0, v1;
      // ---- stage 1: h1 pair = relu(Wd0 @ z + bd0) ----
      a0 = a1 = b0 = b1 = 0.0f;
      {
        const f4* act = ((const f4*)s_in16) + K1 * 3;
#pragma unroll
        for (int i = 0; i < 2; ++i) {
          f4 q = act[i];
          a0 = dot2f(w0[4*i+0], bch(q.x), a0);
          a1 = dot2f(w0[4*i+1], bch(q.y), a1);
          a0 = dot2f(w0[4*i+2], bch(q.z), a0);
          a1 = dot2f(w0[4*i+3], bch(q.w), a1);
          b0 = dot2f(w0[8+4*i+0], bch(q.x), b0);
          b1 = dot2f(w0[8+4*i+1], bch(q.y), b1);
          b0 = dot2f(w0[8+4*i+2], bch(q.z), b0);
          b1 = dot2f(w0[8+4*i+3], bch(q.w), b1);
        }
      }
      v0 = a0 + a1; v1 = b0 + b1;
      v0 += __shfl_xor(v0, 1); v0 += __shfl_xor(v0, 2); v0 += __shfl_xor(v0, 4);
      v1 += __shfl_xor(v1, 1); v1 += __shfl_xor(v1, 2); v1 += __shfl_xor(v1, 4);
      v0 = fmaxf(v0 + bb00, 0.0f); v1 = fmaxf(v1 + bb01, 0.0f);
      if (K1 == 0) s_a16[(G1 >> 4) * 20 + (G1 & 15)] = pkh(v0, v1);
      __syncthreads();
      // ---- stage 2: h2 pair = relu(Wd1 @ h1 + bd1), streamed weights ----
      a0 = a1 = b0 = b1 = 0.0f;
      {
        const f4* act = ((const f4*)s_a16) + K1 * 5;
        f4 q;
#define SD1(ACC0, ACC1, WV) \
        ACC0 = dot2f(bch(WV.x), bch(q.x), ACC0); \
        ACC1 = dot2f(bch(WV.y), bch(q.y), ACC1); \
        ACC0 = dot2f(bch(WV.z), bch(q.z), ACC0); \
        ACC1 = dot2f(bch(WV.w), bch(q.w), ACC1);
        f4 y4 = wsb[4 * 1024], y5 = wsb[5 * 1024];
        q = act[0]; SD1(a0, a1, y0) SD1(b0, b1, y1)
        f4 y6 = wsb[6 * 1024], y7 = wsb[7 * 1024];
        q = act[1]; SD1(a0, a1, y2) SD1(b0, b1, y3)
        q = act[2]; SD1(a0, a1, y4) SD1(b0, b1, y5)
        q = act[3]; SD1(a0, a1, y6) SD1(b0, b1, y7)
#undef SD1
      }
      v0 = a0 + a1; v1 = b0 + b1;
      v0 += __shfl_xor(v0, 1); v0 += __shfl_xor(v0, 2); v0 += __shfl_xor(v0, 4);
      v1 += __shfl_xor(v1, 1); v1 += __shfl_xor(v1, 2); v1 += __shfl_xor(v1, 4);
      v0 = fmaxf(v0 + bb10, 0.0f); v1 = fmaxf(v1 + bb11, 0.0f);
      if (K1 == 0) s_b16[(G1 >> 3) * 12 + (G1 & 7)] = pkh(v0, v1);
      __syncthreads();
      // ---- stage 3: k pair = Wd2 @ h2 + bd2, fused RK tail ----
      a0 = a1 = b0 = b1 = 0.0f;
      {
        const f4* act = ((const f4*)s_b16) + K3 * 3;
#pragma unroll
        for (int i = 0; i < 2; ++i) {
          f4 q = act[i];
          a0 = dot2f(w2[4*i+0], bch(q.x), a0);
          a1 = dot2f(w2[4*i+1], bch(q.y), a1);
          a0 = dot2f(w2[4*i+2], bch(q.z), a0);
          a1 = dot2f(w2[4*i+3], bch(q.w), a1);
          b0 = dot2f(w2[8+4*i+0], bch(q.x), b0);
          b1 = dot2f(w2[8+4*i+1], bch(q.y), b1);
          b0 = dot2f(w2[8+4*i+2], bch(q.z), b0);
          b1 = dot2f(w2[8+4*i+3], bch(q.w), b1);
        }
      }
      v0 = a0 + a1; v1 = b0 + b1;
      v0 += __shfl_xor(v0, 1); v0 += __shfl_xor(v0, 2);
      v0 += __shfl_xor(v0, 4); v0 += __shfl_xor(v0, 8);
      v1 += __shfl_xor(v1, 1); v1 += __shfl_xor(v1, 2);
      v1 += __shfl_xor(v1, 4); v1 += __shfl_xor(v1, 8);
      float kv0 = v0 + bb20, kv1 = v1 + bb21;
      float z0, z1;
      if (s == 0) {
        k00 = kv0; k01 = kv1;
        z0 = latr0 + hs * (0.2f * kv0);
        z1 = latr1 + hs * (0.2f * kv1);
      } else if (s == 1) {
        k10 = kv0; k11 = kv1;
        z0 = latr0 + hs * ((3.0f/40.0f)*k00 + (9.0f/40.0f)*kv0);
        z1 = latr1 + hs * ((3.0f/40.0f)*k01 + (9.0f/40.0f)*kv1);
      } else if (s == 2) {
        k20 = kv0; k21 = kv1;
        z0 = latr0 + hs * ((44.0f/45.0f)*k00 - (56.0f/15.0f)*k10 + (32.0f/9.0f)*kv0);
        z1 = latr1 + hs * ((44.0f/45.0f)*k01 - (56.0f/15.0f)*k11 + (32.0f/9.0f)*kv1);
      } else if (s == 3) {
        k30 = kv0; k31 = kv1;
        z0 = latr0 + hs * ((19372.0f/6561.0f)*k00 - (25360.0f/2187.0f)*k10
                         + (64448.0f/6561.0f)*k20 - (212.0f/729.0f)*kv0);
        z1 = latr1 + hs * ((19372.0f/6561.0f)*k01 - (25360.0f/2187.0f)*k11
                         + (64448.0f/6561.0f)*k21 - (212.0f/729.0f)*kv1);
      } else if (s == 4) {
        k40 = kv0; k41 = kv1;
        z0 = latr0 + hs * ((9017.0f/3168.0f)*k00 - (355.0f/33.0f)*k10
                         + (46732.0f/5247.0f)*k20 + (49.0f/176.0f)*k30
                         - (5103.0f/18656.0f)*kv0);
        z1 = latr1 + hs * ((9017.0f/3168.0f)*k01 - (355.0f/33.0f)*k11
                         + (46732.0f/5247.0f)*k21 + (49.0f/176.0f)*k31
                         - (5103.0f/18656.0f)*kv1);
      } else {
        z0 = latr0 + hs * ((35.0f/384.0f)*k00 + (500.0f/1113.0f)*k20
                         + (125.0f/192.0f)*k30 - (2187.0f/6784.0f)*k40
                         + (11.0f/84.0f)*kv0);
        z1 = latr1 + hs * ((35.0f/384.0f)*k01 + (500.0f/1113.0f)*k21
                         + (125.0f/192.0f)*k31 - (2187.0f/6784.0f)*k41
                         + (11.0f/84.0f)*kv1);
        latr0 = z0; latr1 = z1;
      }
      if (K3 == 0) {
        s_in16[(G3 >> 3) * 12 + (G3 & 7)] = pkh(z0, z1);
        if (s == 5) { s_lat[2*G3] = z0; s_lat[2*G3 + 1] = z1; }
      }
      __syncthreads();
    }
  };

  // ---- GRU (fp32; Wih/Whh streamed from L2; 384 rows x 2-way K) ----
  auto gru = [&](int ts) {
    __syncthreads();                 // publish s_lat
    float vi = gA, vh = 0.0f;
    const int gr = t >> 1, kh = t & 1;
    if (t < 768) {
      const float* xa = s_acs + ts * ACD + kh * 4;
      const f4* wiv = (const f4*)(Wih + gr * ACD + kh * 4);
      f4 wa = wiv[0];
      vi += wa.x*xa[0] + wa.y*xa[1] + wa.z*xa[2] + wa.w*xa[3];
      const f4* wh = (const f4*)(Whh + gr * LDIM + kh * 64);
      const f4* xl = ((const f4*)s_lat) + kh * 16;
#pragma unroll
      for (int k2 = 0; k2 < 16; ++k2) {
        f4 w = wh[k2], x = xl[k2];
        vh += w.x*x.x + w.y*x.y + w.z*x.z + w.w*x.w;
      }
    }
    vi += __shfl_xor(vi, 1);
    vh += __shfl_xor(vh, 1);
    if (t < 768 && kh == 0) {
      if (gr < LDIM)           s_gr[gr] = vi + vh;
      else if (gr < 2 * LDIM)  s_gz[gr - LDIM] = vi + vh;
      else                   { s_gin[gr - 2*LDIM] = vi; s_ghn[gr - 2*LDIM] = vh; }
    }
    __syncthreads();
    if (t < LDIM) {
      float rg = sigmf(s_gr[t]);
      float zg = sigmf(s_gz[t]);
      float ng = tanhf(s_gin[t] + rg * (s_ghn[t] + bnr));
      float y  = (1.0f - zg) * ng + zg * s_lat[t];
      s_lat[t] = y;
      float ov = __shfl_xor(y, 1);
      if (!(t & 1)) {
        int g = t >> 1;
        s_in16[(g >> 3) * 12 + (g & 7)] = pkh(y, ov);
      }
    }
  };

  // ---- decoder (t<512 uses r13's proven mapping); refreshes latr ----
  auto decode = [&](int ts) {
    __syncthreads();                 // publish s_lat (post-GRU)
    { float2 ld = *(const float2*)(s_lat + 2 * G3); latr0 = ld.x; latr1 = ld.y; }
    if (t < 512) {
      const int p = t >> 1, sub = t & 1;
      float acc = 0.0f;
      {
        const f4* wr = (const f4*)(Wo0 + p * LDIM + sub * 64);
        const f4* xl = ((const f4*)s_lat) + sub * 16;
#pragma unroll
        for (int k2 = 0; k2 < 16; ++k2) {
          f4 w = wr[k2], x = xl[k2];
          acc += w.x*x.x + w.y*x.y + w.z*x.z + w.w*x.w;
        }
      }
      acc += __shfl_xor(acc, 1);
      acc = fmaxf(acc + rb0, 0.0f);
      { float ov = __shfl_xor(acc, 2);
        if ((t & 3) == 0) { int i = t >> 2; s_a16[i + ((i >> 6) << 2)] = pkh(acc, ov); } }
    }
    __syncthreads();
    if (t < 512) {
      const int o  = t >> 4;
      const int sl = t & 15;
      float v2 = 0.0f;
      {
        const f4* wr = (const f4*)(Wo1 + o * HDIM + sl * 16);
        const h2* xs = s_a16 + sl * 8 + ((sl >> 3) << 2);
#pragma unroll
        for (int i = 0; i < 4; ++i) {
          f4 w = wr[i];
          h2 xa = xs[2*i], xb = xs[2*i+1];
          v2 += w.x*(float)xa[0] + w.y*(float)xa[1]
              + w.z*(float)xb[0] + w.w*(float)xb[1];
        }
      }
      v2 += __shfl_xor(v2, 1);
      v2 += __shfl_xor(v2, 2);
      v2 += __shfl_xor(v2, 4);
      v2 += __shfl_xor(v2, 8);
      if (sl == 0) out[((size_t)b * NT + ts) * OBD + o] = v2 + bo1[o];
    }
    __syncthreads();                 // protect s_a16 before next substep
  };

  // ================= init + encoder =================
  if (t < OBD) s_obs[t] = ob[b * OBD + t];
  if (t < NT)  s_times[t] = times[b * NT + t];
  if (t < NT * ACD) s_acs[t] = acs[(size_t)b * NT * ACD + t];
  __syncthreads();
  if (t < HDIM) {
    float acc = be0[t];
    const float* wr = We0 + t * OBD;
#pragma unroll
    for (int j = 0; j < OBD; ++j) acc += wr[j] * s_obs[j];
    s_tmp[t] = fmaxf(acc, 0.0f);
  }
  __syncthreads();
  {
    const int rr = t >> 3, kk = t & 7;   // encoder: row rr, K-eighth kk
    const f4* wr = (const f4*)(We1 + rr * HDIM + kk * 32);
    const f4* xs = ((const f4*)s_tmp) + kk * 8;
    float acc = 0.0f;
#pragma unroll
    for (int k = 0; k < 8; ++k) {
      f4 w = wr[k], x = xs[k];
      acc += w.x*x.x + w.y*x.y + w.z*x.z + w.w*x.w;
    }
    acc += __shfl_xor(acc, 1);
    acc += __shfl_xor(acc, 2);
    acc += __shfl_xor(acc, 4);
    if (kk == 0) s_lat[rr] = acc + be1[rr];
  }

  // ================= time loop =================
  gru(0);
  decode(0);

#pragma unroll 1
  for (int ts = 1; ts < NT; ++ts) {
    float hs = 0.25f * (s_times[ts] - s_times[ts - 1]);
#pragma unroll 1
    for (int su = 0; su < 4; ++su) substep(hs);
    gru(ts);
    decode(ts);
  }
}

extern "C" void kernel_launch(void* const* d_in, const int* in_sizes, int n_in,
                              void* d_out, int out_size, void* d_ws, size_t ws_size,
                              hipStream_t stream) {
  (void)in_sizes; (void)n_in; (void)ws_size; (void)out_size;
  const float* ob    = (const float*)d_in[0];
  const float* acs   = (const float*)d_in[1];
  const float* times = (const float*)d_in[2];
  const float* We0   = (const float*)d_in[3];
  const float* be0   = (const float*)d_in[4];
  const float* We1   = (const float*)d_in[5];
  const float* be1   = (const float*)d_in[6];
  const float* Wd0   = (const float*)d_in[7];
  const float* bd0   = (const float*)d_in[8];
  const float* Wd1   = (const float*)d_in[9];
  const float* bd1   = (const float*)d_in[10];
  const float* Wd2   = (const float*)d_in[11];
  const float* bd2   = (const float*)d_in[12];
  const float* Wo0   = (const float*)d_in[13];
  const float* bo0   = (const float*)d_in[14];
  const float* Wo1   = (const float*)d_in[15];
  const float* bo1   = (const float*)d_in[16];
  const float* Wih   = (const float*)d_in[17];
  const float* Whh   = (const float*)d_in[18];
  const float* bih   = (const float*)d_in[19];
  const float* bn    = (const float*)d_in[20];

  f4* ws4 = (f4*)d_ws;   // 8 chunks x 1024 threads x 16 B = 131072 B

  prep_w1<<<dim3(8), dim3(1024), 0, stream>>>(Wd1, ws4);
  ode_rnn_kernel<<<dim3(NBATCH), dim3(1024), 0, stream>>>(
      ob, acs, times, We0, be0, We1, be1, Wd0, bd0, bd1, Wd2, bd2,
      Wo0, bo0, Wo1, bo1, Wih, Whh, bih, bn, ws4, (float*)d_out);
}

// Round 15
// 2747.696 us; speedup vs baseline: 1.1313x; 1.1313x over previous
//
#include <hip/hip_runtime.h>
#include <stdint.h>

#define NBATCH 128
#define NT     64
#define OBD    32
#define ACD    8
#define LDIM   128
#define HDIM   256

typedef _Float16 h2 __attribute__((ext_vector_type(2)));
typedef float    f4 __attribute__((ext_vector_type(4)));

#if defined(__has_builtin)
#  if __has_builtin(__builtin_amdgcn_fdot2)
#    define HAVE_FDOT2 1
#  endif
#endif

__device__ __forceinline__ float dot2f(h2 a, h2 b, float c) {
#ifdef HAVE_FDOT2
  return __builtin_amdgcn_fdot2(a, b, c, false);
#else
  return c + (float)a[0] * (float)b[0] + (float)a[1] * (float)b[1];
#endif
}

__device__ __forceinline__ h2 pkh(float a, float b) {
  h2 r; r[0] = (_Float16)a; r[1] = (_Float16)b; return r;
}

__device__ __forceinline__ h2 bch(float x) { return __builtin_bit_cast(h2, x); }
__device__ __forceinline__ float fch(h2 x) { return __builtin_bit_cast(float, x); }

__device__ __forceinline__ float sigmf(float x) { return 1.0f / (1.0f + expf(-x)); }

#define DOT4(W, I, Q) \
    a0 = dot2f(W[4*(I)+0], bch(Q.x), a0); \
    a1 = dot2f(W[4*(I)+1], bch(Q.y), a1); \
    a2 = dot2f(W[4*(I)+2], bch(Q.z), a2); \
    a3 = dot2f(W[4*(I)+3], bch(Q.w), a3);

// AGPR read of 8 w1 entries into a named VGPR buffer (static indices).
#define AREAD8(BUF, BASE) \
  asm("v_accvgpr_read_b32 %0, %1" : "=v"(BUF[0]) : "a"(w1a[(BASE)+0])); \
  asm("v_accvgpr_read_b32 %0, %1" : "=v"(BUF[1]) : "a"(w1a[(BASE)+1])); \
  asm("v_accvgpr_read_b32 %0, %1" : "=v"(BUF[2]) : "a"(w1a[(BASE)+2])); \
  asm("v_accvgpr_read_b32 %0, %1" : "=v"(BUF[3]) : "a"(w1a[(BASE)+3])); \
  asm("v_accvgpr_read_b32 %0, %1" : "=v"(BUF[4]) : "a"(w1a[(BASE)+4])); \
  asm("v_accvgpr_read_b32 %0, %1" : "=v"(BUF[5]) : "a"(w1a[(BASE)+5])); \
  asm("v_accvgpr_read_b32 %0, %1" : "=v"(BUF[6]) : "a"(w1a[(BASE)+6])); \
  asm("v_accvgpr_read_b32 %0, %1" : "=v"(BUF[7]) : "a"(w1a[(BASE)+7]));

// dots for act f4 chunks I0, I0+1 against an 8-entry w1 buffer
#define DOT8(BUF, I0) { \
  f4 q = act[(I0)]; \
  a0 = dot2f(bch(BUF[0]), bch(q.x), a0); \
  a1 = dot2f(bch(BUF[1]), bch(q.y), a1); \
  a2 = dot2f(bch(BUF[2]), bch(q.z), a2); \
  a3 = dot2f(bch(BUF[3]), bch(q.w), a3); \
  q = act[(I0)+1]; \
  a0 = dot2f(bch(BUF[4]), bch(q.x), a0); \
  a1 = dot2f(bch(BUF[5]), bch(q.y), a1); \
  a2 = dot2f(bch(BUF[6]), bch(q.z), a2); \
  a3 = dot2f(bch(BUF[7]), bch(q.w), a3); }

// LDS K-slice padding (h2 elem = 1 dword; bank = dword % 32): slice bases
// offset +4 dwords mod 32 -> K-half runs on disjoint banks (r10: 1.04e8 ->
// 4.4e6 conflict-cycles).
#define PI(i) ((i) + (((i) >> 5) << 2))
#define PA(i) ((i) + (((i) >> 6) << 2))
#define PB(i) ((i) + (((i) >> 5) << 2))

// 512 threads. H-stages: row p=t>>1, K-half sub=t&1. L-stages: row r=t>>2,
// K-quarter ksub=t&3. Weight placement (r1-r14 ledger): allocator hard-caps
// arch VGPRs at 128 for 512-thr blocks (2-block-residency heuristic; 1024
// thr -> 64). w0/w2 resident in the 128; w1 (64 h2) lives in AGPRs --
// 128 arch + 64 AGPR = 192/wave, 2 waves/SIMD, NO memory traffic per use.
// r8 proved the AGPR write/read mechanism; its cost was inline reads on the
// critical path. Here reads are software-pipelined: 8-entry ping-pong
// buffers, group g+1 reads (pure VALU) interleave with group g dots; group
// 0 reads issue during stage 1. RK state k0..k4 + lat[r] in per-lane regs.
__global__ __attribute__((amdgpu_waves_per_eu(2, 2))) __launch_bounds__(512)
void ode_rnn_kernel(const float* __restrict__ ob,   const float* __restrict__ acs,
                    const float* __restrict__ times,
                    const float* __restrict__ We0,  const float* __restrict__ be0,
                    const float* __restrict__ We1,  const float* __restrict__ be1,
                    const float* __restrict__ Wd0,  const float* __restrict__ bd0,
                    const float* __restrict__ Wd1,  const float* __restrict__ bd1,
                    const float* __restrict__ Wd2,  const float* __restrict__ bd2,
                    const float* __restrict__ Wo0,  const float* __restrict__ bo0,
                    const float* __restrict__ Wo1,  const float* __restrict__ bo1,
                    const float* __restrict__ Wih,  const float* __restrict__ Whh,
                    const float* __restrict__ bih,  const float* __restrict__ bn,
                    float* __restrict__ out)
{
  const int t    = threadIdx.x;
  const int b    = blockIdx.x;
  const int p    = t >> 1;           // 0..255  H-stage row
  const int sub  = t & 1;            // K-half
  const int r    = t >> 2;           // 0..127  L-stage row
  const int ksub = t & 3;            // K-quarter

  __shared__ __align__(16) float s_lat[LDIM];
  __shared__ __align__(16) float s_gz[LDIM];
  __shared__ __align__(16) float s_gin[LDIM];
  __shared__ __align__(16) float s_ghn[LDIM];
  __shared__ __align__(16) float s_tmp[HDIM];
  __shared__ __align__(16) float s_obs[OBD];
  __shared__ __align__(16) float s_times[NT];
  __shared__ __align__(16) float s_acs[NT * ACD];
  __shared__ __align__(16) h2    s_in16[68];    // 2 x (32 h2 + 4 pad)
  __shared__ __align__(16) h2    s_a16[132];    // 2 x (64 h2 + 4 pad)
  __shared__ __align__(16) h2    s_b16[140];    // 4 x (32 h2 + 4 pad)

  // ---- arch-VGPR weights: Wd0 half-row + Wd2 quarter-row (64 h2) ----
  h2 w0[32], w2[32];
  {
    const float2* pp = (const float2*)(Wd0 + p * LDIM + sub * 64);
#pragma unroll
    for (int i = 0; i < 32; ++i) { float2 v = pp[i]; w0[i] = pkh(v.x, v.y); }
  }
  {
    const float2* pp = (const float2*)(Wd2 + r * HDIM + ksub * 64);
#pragma unroll
    for (int i = 0; i < 32; ++i) { float2 v = pp[i]; w2[i] = pkh(v.x, v.y); }
  }
  // ---- AGPR weights: Wd1 half-row, 64 h2 as f32 bit-patterns (r8) ----
  float w1a[64];
  {
    const float2* pp = (const float2*)(Wd1 + p * HDIM + sub * 128);
#pragma unroll
    for (int i = 0; i < 64; ++i) {
      float2 v = pp[i];
      float packed = fch(pkh(v.x, v.y));
      asm("v_accvgpr_write_b32 %0, %1" : "=a"(w1a[i]) : "v"(packed));
    }
  }

  const float bb0 = bd0[p];
  const float bb1 = bd1[p];
  const float bb2 = bd2[r];
  const float rb0 = bo0[p];
  const float gA  = (t < 3 * LDIM) ? bih[t] : 0.0f;
  const float bnr = (t < LDIM) ? bn[t] : 0.0f;

  float latr = 0.0f;                 // lat[r], refreshed in decode()

  // ---- one Dopri5 substep; entry: s_in16 = packed lat, latr = lat[r] ----
  auto substep = [&](float hs) {
    float k0 = 0, k1 = 0, k2 = 0, k3 = 0, k4 = 0;
#pragma unroll
    for (int s = 0; s < 6; ++s) {
      float a0, a1, a2, a3, v;
      float ga[8], gb[8];
      // group-0 w1 reads: pure VALU, no deps -> fill stage-1 stall slots
      AREAD8(ga, 0)
      // stage 1: h1 = relu(Wd0 @ z + bd0)
      a0 = a1 = a2 = a3 = 0.0f;
      {
        const f4* src = ((const f4*)s_in16) + sub * 9;
#pragma unroll
        for (int i = 0; i < 8; ++i) { f4 q = src[i]; DOT4(w0, i, q) }
      }
      v = (a0 + a1) + (a2 + a3);
      v += __shfl_xor(v, 1);
      v = fmaxf(v + bb0, 0.0f);
      { float ov = __shfl_xor(v, 2); if ((t & 3) == 0) s_a16[PA(t >> 2)] = pkh(v, ov); }
      __syncthreads();
      // stage 2: h2 = relu(Wd1 @ h1 + bd1)
      // AGPR reads of group g+1 pipelined against dots of group g.
      a0 = a1 = a2 = a3 = 0.0f;
      {
        const f4* act = ((const f4*)s_a16) + sub * 17;
        AREAD8(gb, 8)   DOT8(ga, 0)
        AREAD8(ga, 16)  DOT8(gb, 2)
        AREAD8(gb, 24)  DOT8(ga, 4)
        AREAD8(ga, 32)  DOT8(gb, 6)
        AREAD8(gb, 40)  DOT8(ga, 8)
        AREAD8(ga, 48)  DOT8(gb, 10)
        AREAD8(gb, 56)  DOT8(ga, 12)
        DOT8(gb, 14)
      }
      v = (a0 + a1) + (a2 + a3);
      v += __shfl_xor(v, 1);
      v = fmaxf(v + bb1, 0.0f);
      { float ov = __shfl_xor(v, 2); if ((t & 3) == 0) s_b16[PB(t >> 2)] = pkh(v, ov); }
      __syncthreads();
      // stage 3: k_s = Wd2 @ h2 + bd2, fused RK tail
      a0 = a1 = a2 = a3 = 0.0f;
      {
        const f4* src = ((const f4*)s_b16) + ksub * 9;
#pragma unroll
        for (int i = 0; i < 8; ++i) { f4 q = src[i]; DOT4(w2, i, q) }
      }
      v = (a0 + a1) + (a2 + a3);
      v += __shfl_xor(v, 1);
      v += __shfl_xor(v, 2);
      float kv = v + bb2;              // k_s[r], in every lane of the quad
      float z;
      if (s == 0) {
        k0 = kv; z = latr + hs * (0.2f * kv);
      } else if (s == 1) {
        k1 = kv; z = latr + hs * ((3.0f/40.0f)*k0 + (9.0f/40.0f)*kv);
      } else if (s == 2) {
        k2 = kv; z = latr + hs * ((44.0f/45.0f)*k0 - (56.0f/15.0f)*k1
                                + (32.0f/9.0f)*kv);
      } else if (s == 3) {
        k3 = kv; z = latr + hs * ((19372.0f/6561.0f)*k0 - (25360.0f/2187.0f)*k1
                                + (64448.0f/6561.0f)*k2 - (212.0f/729.0f)*kv);
      } else if (s == 4) {
        k4 = kv; z = latr + hs * ((9017.0f/3168.0f)*k0 - (355.0f/33.0f)*k1
                                + (46732.0f/5247.0f)*k2 + (49.0f/176.0f)*k3
                                - (5103.0f/18656.0f)*kv);
      } else {
        z = latr + hs * ((35.0f/384.0f)*k0 + (500.0f/1113.0f)*k2
                       + (125.0f/192.0f)*k3 - (2187.0f/6784.0f)*k4
                       + (11.0f/84.0f)*kv);
        latr = z;
      }
      { float ov = __shfl_xor(z, 4); if ((t & 7) == 0) s_in16[PI(t >> 3)] = pkh(z, ov); }
      if (s == 5 && ksub == 0) s_lat[r] = z;
      __syncthreads();
    }
  };

  // ---- GRU (fp32; Wih/Whh streamed from L2) ----
  auto gru = [&](int ts) {
    __syncthreads();                 // publish s_lat
    float vi = gA, vh = 0.0f;
    if (t < 3 * LDIM) {
      const float* xa = s_acs + ts * ACD;
      const f4* wiv = (const f4*)(Wih + t * ACD);
      f4 wa = wiv[0], wb = wiv[1];
      vi += wa.x*xa[0] + wa.y*xa[1] + wa.z*xa[2] + wa.w*xa[3]
          + wb.x*xa[4] + wb.y*xa[5] + wb.z*xa[6] + wb.w*xa[7];
      const f4* wh = (const f4*)(Whh + t * LDIM);
      const f4* xl = (const f4*)s_lat;
#pragma unroll
      for (int k2 = 0; k2 < LDIM / 4; ++k2) {
        f4 w = wh[k2], x = xl[k2];
        vh += w.x*x.x + w.y*x.y + w.z*x.z + w.w*x.w;
      }
    }
    if (t >= LDIM && t < 2 * LDIM)          s_gz[t - LDIM] = vi + vh;
    else if (t >= 2 * LDIM && t < 3 * LDIM) { s_gin[t - 2*LDIM] = vi; s_ghn[t - 2*LDIM] = vh; }
    __syncthreads();
    if (t < LDIM) {
      float rg = sigmf(vi + vh);
      float zg = sigmf(s_gz[t]);
      float ng = tanhf(s_gin[t] + rg * (s_ghn[t] + bnr));
      float y  = (1.0f - zg) * ng + zg * s_lat[t];
      s_lat[t] = y;
      float ov = __shfl_xor(y, 1);
      if (!(t & 1)) s_in16[PI(t >> 1)] = pkh(y, ov);
    }
  };

  // ---- decoder: Wo0/Wo1 streamed f32 from L2; also refreshes latr ----
  auto decode = [&](int ts) {
    __syncthreads();                 // publish s_lat (post-GRU)
    latr = s_lat[r];                 // register copy for the next substeps
    float acc = 0.0f;
    {
      const f4* wr = (const f4*)(Wo0 + p * LDIM + sub * 64);
      const f4* xl = ((const f4*)s_lat) + sub * 16;
#pragma unroll
      for (int k2 = 0; k2 < 16; ++k2) {
        f4 w = wr[k2], x = xl[k2];
        acc += w.x*x.x + w.y*x.y + w.z*x.z + w.w*x.w;
      }
    }
    acc += __shfl_xor(acc, 1);
    acc = fmaxf(acc + rb0, 0.0f);
    { float ov = __shfl_xor(acc, 2); if ((t & 3) == 0) s_a16[PA(t >> 2)] = pkh(acc, ov); }
    __syncthreads();
    // stage B: out row o = t>>4, K-slice sl = t&15 (16 of 256)
    const int o  = t >> 4;
    const int sl = t & 15;
    float v2 = 0.0f;
    {
      const f4* wr = (const f4*)(Wo1 + o * HDIM + sl * 16);
      const h2* xs = s_a16 + sl * 8 + ((sl >> 3) << 2);   // padded slices
#pragma unroll
      for (int i = 0; i < 4; ++i) {
        f4 w = wr[i];
        h2 xa = xs[2*i], xb = xs[2*i+1];
        v2 += w.x*(float)xa[0] + w.y*(float)xa[1]
            + w.z*(float)xb[0] + w.w*(float)xb[1];
      }
    }
    v2 += __shfl_xor(v2, 1);
    v2 += __shfl_xor(v2, 2);
    v2 += __shfl_xor(v2, 4);
    v2 += __shfl_xor(v2, 8);
    if (sl == 0) out[((size_t)b * NT + ts) * OBD + o] = v2 + bo1[o];
    __syncthreads();                 // protect s_a16 before next substep
  };

  // ================= init + encoder =================
  if (t < OBD) s_obs[t] = ob[b * OBD + t];
  if (t < NT)  s_times[t] = times[b * NT + t];
  s_acs[t] = acs[(size_t)b * NT * ACD + t];   // NT*ACD == 512 == blockDim
  __syncthreads();
  if (t < HDIM) {
    float acc = be0[t];
    const float* wr = We0 + t * OBD;
#pragma unroll
    for (int j = 0; j < OBD; ++j) acc += wr[j] * s_obs[j];
    s_tmp[t] = fmaxf(acc, 0.0f);
  }
  __syncthreads();
  {
    const f4* wr = (const f4*)(We1 + r * HDIM + ksub * 64);
    const f4* xs = ((const f4*)s_tmp) + ksub * 16;
    float acc = 0.0f;
#pragma unroll
    for (int k = 0; k < 16; ++k) {
      f4 w = wr[k], x = xs[k];
      acc += w.x*x.x + w.y*x.y + w.z*x.z + w.w*x.w;
    }
    acc += __shfl_xor(acc, 1);
    acc += __shfl_xor(acc, 2);
    if (ksub == 0) s_lat[r] = acc + be1[r];
  }

  // ================= time loop =================
  gru(0);
  decode(0);

#pragma unroll 1
  for (int ts = 1; ts < NT; ++ts) {
    float hs = 0.25f * (s_times[ts] - s_times[ts - 1]);
#pragma unroll 1
    for (int su = 0; su < 4; ++su) substep(hs);
    gru(ts);
    decode(ts);
  }
}

extern "C" void kernel_launch(void* const* d_in, const int* in_sizes, int n_in,
                              void* d_out, int out_size, void* d_ws, size_t ws_size,
                              hipStream_t stream) {
  (void)in_sizes; (void)n_in; (void)d_ws; (void)ws_size; (void)out_size;
  const float* ob    = (const float*)d_in[0];
  const float* acs   = (const float*)d_in[1];
  const float* times = (const float*)d_in[2];
  const float* We0   = (const float*)d_in[3];
  const float* be0   = (const float*)d_in[4];
  const float* We1   = (const float*)d_in[5];
  const float* be1   = (const float*)d_in[6];
  const float* Wd0   = (const float*)d_in[7];
  const float* bd0   = (const float*)d_in[8];
  const float* Wd1   = (const float*)d_in[9];
  const float* bd1   = (const float*)d_in[10];
  const float* Wd2   = (const float*)d_in[11];
  const float* bd2   = (const float*)d_in[12];
  const float* Wo0   = (const float*)d_in[13];
  const float* bo0   = (const float*)d_in[14];
  const float* Wo1   = (const float*)d_in[15];
  const float* bo1   = (const float*)d_in[16];
  const float* Wih   = (const float*)d_in[17];
  const float* Whh   = (const float*)d_in[18];
  const float* bih   = (const float*)d_in[19];
  const float* bn    = (const float*)d_in[20];

  ode_rnn_kernel<<<dim3(NBATCH), dim3(512), 0, stream>>>(
      ob, acs, times, We0, be0, We1, be1, Wd0, bd0, Wd1, bd1, Wd2, bd2,
      Wo0, bo0, Wo1, bo1, Wih, Whh, bih, bn, (float*)d_out);
}

// Round 16
// 2332.018 us; speedup vs baseline: 1.3330x; 1.1782x over previous
//
#include <hip/hip_runtime.h>
#include <stdint.h>

#define NBATCH 128
#define NT     64
#define OBD    32
#define ACD    8
#define LDIM   128
#define HDIM   256

typedef _Float16 h2 __attribute__((ext_vector_type(2)));
typedef float    f4 __attribute__((ext_vector_type(4)));

#if defined(__has_builtin)
#  if __has_builtin(__builtin_amdgcn_fdot2)
#    define HAVE_FDOT2 1
#  endif
#endif

__device__ __forceinline__ float dot2f(h2 a, h2 b, float c) {
#ifdef HAVE_FDOT2
  return __builtin_amdgcn_fdot2(a, b, c, false);
#else
  return c + (float)a[0] * (float)b[0] + (float)a[1] * (float)b[1];
#endif
}

__device__ __forceinline__ h2 pkh(float a, float b) {
  h2 r; r[0] = (_Float16)a; r[1] = (_Float16)b; return r;
}

__device__ __forceinline__ h2 bch(float x) { return __builtin_bit_cast(h2, x); }
__device__ __forceinline__ float fch(h2 x) { return __builtin_bit_cast(float, x); }

__device__ __forceinline__ float sigmf(float x) { return 1.0f / (1.0f + expf(-x)); }

#define DOT4(W, I, Q) \
    a0 = dot2f(W[4*(I)+0], bch(Q.x), a0); \
    a1 = dot2f(W[4*(I)+1], bch(Q.y), a1); \
    a2 = dot2f(W[4*(I)+2], bch(Q.z), a2); \
    a3 = dot2f(W[4*(I)+3], bch(Q.w), a3);

// LDS K-slice padding (h2 elem = 1 dword; bank = dword % 32): slice bases
// offset +4 dwords mod 32 -> K-half runs on disjoint banks (r10: 1.04e8 ->
// 4.4e6 conflict-cycles).
#define PI(i) ((i) + (((i) >> 5) << 2))
#define PA(i) ((i) + (((i) >> 6) << 2))
#define PB(i) ((i) + (((i) >> 5) << 2))

// ---- prep: Wd1 (f32, row-major) -> d_ws as f16, chunk-major interleave.
// ws4[j*512 + t] = f4 of 8 packed halfs = Wd1[row(t)][sub(t)*128 + 8j .. +7].
__global__ void prep_w1(const float* __restrict__ Wd1, f4* __restrict__ ws4) {
  int idx = blockIdx.x * blockDim.x + threadIdx.x;   // 0..8191
  int j  = idx >> 9;
  int tt = idx & 511;
  const float* src = Wd1 + (tt >> 1) * HDIM + (tt & 1) * 128 + j * 8;
  f4 c;
  c.x = fch(pkh(src[0], src[1]));
  c.y = fch(pkh(src[2], src[3]));
  c.z = fch(pkh(src[4], src[5]));
  c.w = fch(pkh(src[6], src[7]));
  ws4[j * 512 + tt] = c;
}

// r12 base (best: 2317us) + three chain/sync trims (r12/r13/r15 regime
// diagnosis: dependency-chain + barrier-overhead bound; parallel-work
// changes are free, critical-path work is ~2x amplified):
//  (1) gru() entry barrier removed (duplicated substep's trailing barrier).
//  (2) stage-2 uses 8 accumulators (serial dot depth 16 -> 8).
//  (3) 6 w1 chunks prefetched pre-barrier (was 4); in-flight cap unchanged.
__global__ __attribute__((amdgpu_waves_per_eu(2, 2))) __launch_bounds__(512)
void ode_rnn_kernel(const float* __restrict__ ob,   const float* __restrict__ acs,
                    const float* __restrict__ times,
                    const float* __restrict__ We0,  const float* __restrict__ be0,
                    const float* __restrict__ We1,  const float* __restrict__ be1,
                    const float* __restrict__ Wd0,  const float* __restrict__ bd0,
                    const float* __restrict__ bd1,
                    const float* __restrict__ Wd2,  const float* __restrict__ bd2,
                    const float* __restrict__ Wo0,  const float* __restrict__ bo0,
                    const float* __restrict__ Wo1,  const float* __restrict__ bo1,
                    const float* __restrict__ Wih,  const float* __restrict__ Whh,
                    const float* __restrict__ bih,  const float* __restrict__ bn,
                    const f4* __restrict__ ws4,
                    float* __restrict__ out)
{
  const int t    = threadIdx.x;
  const int b    = blockIdx.x;
  const int p    = t >> 1;           // 0..255  H-stage row
  const int sub  = t & 1;            // K-half
  const int r    = t >> 2;           // 0..127  L-stage row
  const int ksub = t & 3;            // K-quarter

  __shared__ __align__(16) float s_lat[LDIM];
  __shared__ __align__(16) float s_gz[LDIM];
  __shared__ __align__(16) float s_gin[LDIM];
  __shared__ __align__(16) float s_ghn[LDIM];
  __shared__ __align__(16) float s_tmp[HDIM];
  __shared__ __align__(16) float s_obs[OBD];
  __shared__ __align__(16) float s_times[NT];
  __shared__ __align__(16) float s_acs[NT * ACD];
  __shared__ __align__(16) h2    s_in16[68];    // 2 x (32 h2 + 4 pad)
  __shared__ __align__(16) h2    s_a16[132];    // 2 x (64 h2 + 4 pad)
  __shared__ __align__(16) h2    s_b16[140];    // 4 x (32 h2 + 4 pad)

  // ---- resident register weights: Wd0 half-row + Wd2 quarter-row ----
  h2 w0[32], w2[32];
  {
    const float2* pp = (const float2*)(Wd0 + p * LDIM + sub * 64);
#pragma unroll
    for (int i = 0; i < 32; ++i) { float2 v = pp[i]; w0[i] = pkh(v.x, v.y); }
  }
  {
    const float2* pp = (const float2*)(Wd2 + r * HDIM + ksub * 64);
#pragma unroll
    for (int i = 0; i < 32; ++i) { float2 v = pp[i]; w2[i] = pkh(v.x, v.y); }
  }
  const f4* wsb = ws4 + t;           // per-thread w1 stream base

  const float bb0 = bd0[p];
  const float bb1 = bd1[p];
  const float bb2 = bd2[r];
  const float rb0 = bo0[p];
  const float gA  = (t < 3 * LDIM) ? bih[t] : 0.0f;
  const float bnr = (t < LDIM) ? bn[t] : 0.0f;

  float latr = 0.0f;                 // lat[r], refreshed in decode()

  // ---- one Dopri5 substep; entry: s_in16 = packed lat, latr = lat[r] ----
  auto substep = [&](float hs) {
    float k0 = 0, k1 = 0, k2 = 0, k3 = 0, k4 = 0;
#pragma unroll
    for (int s = 0; s < 6; ++s) {
      float a0, a1, a2, a3, v;
      // w1 prefetch chunks 0-5: no deps -> issue now, land by stage 2
      f4 y0 = wsb[0 * 512], y1 = wsb[1 * 512];
      f4 y2 = wsb[2 * 512], y3 = wsb[3 * 512];
      f4 y4 = wsb[4 * 512], y5 = wsb[5 * 512];
      // stage 1: h1 = relu(Wd0 @ z + bd0)
      a0 = a1 = a2 = a3 = 0.0f;
      {
        const f4* src = ((const f4*)s_in16) + sub * 9;
#pragma unroll
        for (int i = 0; i < 8; ++i) { f4 q = src[i]; DOT4(w0, i, q) }
      }
      v = (a0 + a1) + (a2 + a3);
      v += __shfl_xor(v, 1);
      v = fmaxf(v + bb0, 0.0f);
      { float ov = __shfl_xor(v, 2); if ((t & 3) == 0) s_a16[PA(t >> 2)] = pkh(v, ov); }
      __syncthreads();
      // stage 2: h2 = relu(Wd1 @ h1 + bd1) -- streamed weights, 8 accs
      float b0, b1, b2, b3;
      a0 = a1 = a2 = a3 = b0 = b1 = b2 = b3 = 0.0f;
      {
        const f4* act = ((const f4*)s_a16) + sub * 17;
        f4 q;
#define SDA(WV, J) q = act[J]; \
        a0 = dot2f(bch(WV.x), bch(q.x), a0); \
        a1 = dot2f(bch(WV.y), bch(q.y), a1); \
        a2 = dot2f(bch(WV.z), bch(q.z), a2); \
        a3 = dot2f(bch(WV.w), bch(q.w), a3);
#define SDB(WV, J) q = act[J]; \
        b0 = dot2f(bch(WV.x), bch(q.x), b0); \
        b1 = dot2f(bch(WV.y), bch(q.y), b1); \
        b2 = dot2f(bch(WV.z), bch(q.z), b2); \
        b3 = dot2f(bch(WV.w), bch(q.w), b3);
        SDA(y0, 0)  SDB(y1, 1)
        f4 y6 = wsb[6 * 512],  y7 = wsb[7 * 512];
        SDA(y2, 2)  SDB(y3, 3)
        f4 y8 = wsb[8 * 512],  y9 = wsb[9 * 512];
        SDA(y4, 4)  SDB(y5, 5)
        f4 y10 = wsb[10 * 512], y11 = wsb[11 * 512];
        SDA(y6, 6)  SDB(y7, 7)
        f4 y12 = wsb[12 * 512], y13 = wsb[13 * 512];
        SDA(y8, 8)  SDB(y9, 9)
        f4 y14 = wsb[14 * 512], y15 = wsb[15 * 512];
        SDA(y10, 10) SDB(y11, 11)
        SDA(y12, 12) SDB(y13, 13)
        SDA(y14, 14) SDB(y15, 15)
#undef SDA
#undef SDB
      }
      v = ((a0 + a1) + (a2 + a3)) + ((b0 + b1) + (b2 + b3));
      v += __shfl_xor(v, 1);
      v = fmaxf(v + bb1, 0.0f);
      { float ov = __shfl_xor(v, 2); if ((t & 3) == 0) s_b16[PB(t >> 2)] = pkh(v, ov); }
      __syncthreads();
      // stage 3: k_s = Wd2 @ h2 + bd2, fused RK tail
      a0 = a1 = a2 = a3 = 0.0f;
      {
        const f4* src = ((const f4*)s_b16) + ksub * 9;
#pragma unroll
        for (int i = 0; i < 8; ++i) { f4 q = src[i]; DOT4(w2, i, q) }
      }
      v = (a0 + a1) + (a2 + a3);
      v += __shfl_xor(v, 1);
      v += __shfl_xor(v, 2);
      float kv = v + bb2;              // k_s[r], in every lane of the quad
      float z;
      if (s == 0) {
        k0 = kv; z = latr + hs * (0.2f * kv);
      } else if (s == 1) {
        k1 = kv; z = latr + hs * ((3.0f/40.0f)*k0 + (9.0f/40.0f)*kv);
      } else if (s == 2) {
        k2 = kv; z = latr + hs * ((44.0f/45.0f)*k0 - (56.0f/15.0f)*k1
                                + (32.0f/9.0f)*kv);
      } else if (s == 3) {
        k3 = kv; z = latr + hs * ((19372.0f/6561.0f)*k0 - (25360.0f/2187.0f)*k1
                                + (64448.0f/6561.0f)*k2 - (212.0f/729.0f)*kv);
      } else if (s == 4) {
        k4 = kv; z = latr + hs * ((9017.0f/3168.0f)*k0 - (355.0f/33.0f)*k1
                                + (46732.0f/5247.0f)*k2 + (49.0f/176.0f)*k3
                                - (5103.0f/18656.0f)*kv);
      } else {
        z = latr + hs * ((35.0f/384.0f)*k0 + (500.0f/1113.0f)*k2
                       + (125.0f/192.0f)*k3 - (2187.0f/6784.0f)*k4
                       + (11.0f/84.0f)*kv);
        latr = z;
      }
      { float ov = __shfl_xor(z, 4); if ((t & 7) == 0) s_in16[PI(t >> 3)] = pkh(z, ov); }
      if (s == 5 && ksub == 0) s_lat[r] = z;
      __syncthreads();
    }
  };

  // ---- GRU (fp32; Wih/Whh streamed from L2). Entry: s_lat published by
  // caller (substep trailing barrier / explicit post-encoder barrier) ----
  auto gru = [&](int ts) {
    float vi = gA, vh = 0.0f;
    if (t < 3 * LDIM) {
      const float* xa = s_acs + ts * ACD;
      const f4* wiv = (const f4*)(Wih + t * ACD);
      f4 wa = wiv[0], wb = wiv[1];
      vi += wa.x*xa[0] + wa.y*xa[1] + wa.z*xa[2] + wa.w*xa[3]
          + wb.x*xa[4] + wb.y*xa[5] + wb.z*xa[6] + wb.w*xa[7];
      const f4* wh = (const f4*)(Whh + t * LDIM);
      const f4* xl = (const f4*)s_lat;
#pragma unroll
      for (int k2 = 0; k2 < LDIM / 4; ++k2) {
        f4 w = wh[k2], x = xl[k2];
        vh += w.x*x.x + w.y*x.y + w.z*x.z + w.w*x.w;
      }
    }
    if (t >= LDIM && t < 2 * LDIM)          s_gz[t - LDIM] = vi + vh;
    else if (t >= 2 * LDIM && t < 3 * LDIM) { s_gin[t - 2*LDIM] = vi; s_ghn[t - 2*LDIM] = vh; }
    __syncthreads();
    if (t < LDIM) {
      float rg = sigmf(vi + vh);
      float zg = sigmf(s_gz[t]);
      float ng = tanhf(s_gin[t] + rg * (s_ghn[t] + bnr));
      float y  = (1.0f - zg) * ng + zg * s_lat[t];
      s_lat[t] = y;
      float ov = __shfl_xor(y, 1);
      if (!(t & 1)) s_in16[PI(t >> 1)] = pkh(y, ov);
    }
  };

  // ---- decoder: Wo0/Wo1 streamed f32 from L2; also refreshes latr ----
  auto decode = [&](int ts) {
    __syncthreads();                 // publish s_lat (post-GRU)
    latr = s_lat[r];                 // register copy for the next substeps
    float acc = 0.0f;
    {
      const f4* wr = (const f4*)(Wo0 + p * LDIM + sub * 64);
      const f4* xl = ((const f4*)s_lat) + sub * 16;
#pragma unroll
      for (int k2 = 0; k2 < 16; ++k2) {
        f4 w = wr[k2], x = xl[k2];
        acc += w.x*x.x + w.y*x.y + w.z*x.z + w.w*x.w;
      }
    }
    acc += __shfl_xor(acc, 1);
    acc = fmaxf(acc + rb0, 0.0f);
    { float ov = __shfl_xor(acc, 2); if ((t & 3) == 0) s_a16[PA(t >> 2)] = pkh(acc, ov); }
    __syncthreads();
    // stage B: out row o = t>>4, K-slice sl = t&15 (16 of 256)
    const int o  = t >> 4;
    const int sl = t & 15;
    float v2 = 0.0f;
    {
      const f4* wr = (const f4*)(Wo1 + o * HDIM + sl * 16);
      const h2* xs = s_a16 + sl * 8 + ((sl >> 3) << 2);   // padded slices
#pragma unroll
      for (int i = 0; i < 4; ++i) {
        f4 w = wr[i];
        h2 xa = xs[2*i], xb = xs[2*i+1];
        v2 += w.x*(float)xa[0] + w.y*(float)xa[1]
            + w.z*(float)xb[0] + w.w*(float)xb[1];
      }
    }
    v2 += __shfl_xor(v2, 1);
    v2 += __shfl_xor(v2, 2);
    v2 += __shfl_xor(v2, 4);
    v2 += __shfl_xor(v2, 8);
    if (sl == 0) out[((size_t)b * NT + ts) * OBD + o] = v2 + bo1[o];
    __syncthreads();                 // protect s_a16 before next substep
  };

  // ================= init + encoder =================
  if (t < OBD) s_obs[t] = ob[b * OBD + t];
  if (t < NT)  s_times[t] = times[b * NT + t];
  s_acs[t] = acs[(size_t)b * NT * ACD + t];   // NT*ACD == 512 == blockDim
  __syncthreads();
  if (t < HDIM) {
    float acc = be0[t];
    const float* wr = We0 + t * OBD;
#pragma unroll
    for (int j = 0; j < OBD; ++j) acc += wr[j] * s_obs[j];
    s_tmp[t] = fmaxf(acc, 0.0f);
  }
  __syncthreads();
  {
    const f4* wr = (const f4*)(We1 + r * HDIM + ksub * 64);
    const f4* xs = ((const f4*)s_tmp) + ksub * 16;
    float acc = 0.0f;
#pragma unroll
    for (int k = 0; k < 16; ++k) {
      f4 w = wr[k], x = xs[k];
      acc += w.x*x.x + w.y*x.y + w.z*x.z + w.w*x.w;
    }
    acc += __shfl_xor(acc, 1);
    acc += __shfl_xor(acc, 2);
    if (ksub == 0) s_lat[r] = acc + be1[r];
  }
  __syncthreads();                   // publish encoder s_lat (gru has no entry barrier)

  // ================= time loop =================
  gru(0);
  decode(0);

#pragma unroll 1
  for (int ts = 1; ts < NT; ++ts) {
    float hs = 0.25f * (s_times[ts] - s_times[ts - 1]);
#pragma unroll 1
    for (int su = 0; su < 4; ++su) substep(hs);
    gru(ts);
    decode(ts);
  }
}

extern "C" void kernel_launch(void* const* d_in, const int* in_sizes, int n_in,
                              void* d_out, int out_size, void* d_ws, size_t ws_size,
                              hipStream_t stream) {
  (void)in_sizes; (void)n_in; (void)ws_size; (void)out_size;
  const float* ob    = (const float*)d_in[0];
  const float* acs   = (const float*)d_in[1];
  const float* times = (const float*)d_in[2];
  const float* We0   = (const float*)d_in[3];
  const float* be0   = (const float*)d_in[4];
  const float* We1   = (const float*)d_in[5];
  const float* be1   = (const float*)d_in[6];
  const float* Wd0   = (const float*)d_in[7];
  const float* bd0   = (const float*)d_in[8];
  const float* Wd1   = (const float*)d_in[9];
  const float* bd1   = (const float*)d_in[10];
  const float* Wd2   = (const float*)d_in[11];
  const float* bd2   = (const float*)d_in[12];
  const float* Wo0   = (const float*)d_in[13];
  const float* bo0   = (const float*)d_in[14];
  const float* Wo1   = (const float*)d_in[15];
  const float* bo1   = (const float*)d_in[16];
  const float* Wih   = (const float*)d_in[17];
  const float* Whh   = (const float*)d_in[18];
  const float* bih   = (const float*)d_in[19];
  const float* bn    = (const float*)d_in[20];

  f4* ws4 = (f4*)d_ws;   // 16 chunks x 512 threads x 16 B = 131072 B

  prep_w1<<<dim3(16), dim3(512), 0, stream>>>(Wd1, ws4);
  ode_rnn_kernel<<<dim3(NBATCH), dim3(512), 0, stream>>>(
      ob, acs, times, We0, be0, We1, be1, Wd0, bd0, bd1, Wd2, bd2,
      Wo0, bo0, Wo1, bo1, Wih, Whh, bih, bn, ws4, (float*)d_out);
}